// Round 1
// baseline (177.135 us; speedup 1.0000x reference)
//
#include <hip/hip_runtime.h>
#include <math.h>

// Layout: sample = 16 lanes x 16 register slots = 256 amplitudes.
// Qubit q in 0..3  -> lane bit  (3-q) of (tid & 15)   (lane xor mask 1<<(3-q))
// Qubit q in 4..7  -> slot bit  (7-q) of r            (reg mask 1<<(7-q))
// Flat state index s = ll*16 + r matches reference bit order (axis i+1 <-> bit 7-i).

template<int CTRL>
__device__ __forceinline__ float dpp_xor(float v) {
    return __int_as_float(__builtin_amdgcn_update_dpp(
        __float_as_int(v), __float_as_int(v), CTRL, 0xF, 0xF, true));
}

template<int MASK>
__device__ __forceinline__ float lxor(float v) {
    static_assert(MASK == 1 || MASK == 2 || MASK == 4 || MASK == 8, "bad mask");
    if constexpr (MASK == 1)      return dpp_xor<0xB1>(v);   // quad_perm [1,0,3,2]
    else if constexpr (MASK == 2) return dpp_xor<0x4E>(v);   // quad_perm [2,3,0,1]
    else if constexpr (MASK == 4) return __int_as_float(__builtin_amdgcn_ds_swizzle(__float_as_int(v), 0x101F));
    else                          return __int_as_float(__builtin_amdgcn_ds_swizzle(__float_as_int(v), 0x201F));
}

// Rot gate on qubit Q. g = {m00r,m00i,m01r,m01i,m10r,m10i,m11r,m11i}
template<int Q>
__device__ __forceinline__ void rot_g(float (&sr)[16], float (&si)[16],
                                      const float* __restrict__ g, int ll)
{
    if constexpr (Q < 4) {
        constexpr int LM = 1 << (3 - Q);
        const int hi = (ll >> (3 - Q)) & 1;
        const float uar = hi ? g[6] : g[0];   // coeff on my amp
        const float uai = hi ? g[7] : g[1];
        const float ubr = hi ? g[4] : g[2];   // coeff on partner amp
        const float ubi = hi ? g[5] : g[3];
        #pragma unroll
        for (int r = 0; r < 16; ++r) {
            const float mr = sr[r], mi = si[r];
            const float pr = lxor<LM>(mr);
            const float pi = lxor<LM>(mi);
            sr[r] = uar*mr - uai*mi + ubr*pr - ubi*pi;
            si[r] = uar*mi + uai*mr + ubr*pi + ubi*pr;
        }
    } else {
        constexpr int RM = 1 << (7 - Q);
        const float g0=g[0],g1=g[1],g2=g[2],g3=g[3],g4=g[4],g5=g[5],g6=g[6],g7=g[7];
        #pragma unroll
        for (int r0 = 0; r0 < 16; ++r0) {
            if ((r0 & RM) == 0) {
                const int r1 = r0 | RM;
                const float a0r=sr[r0], a0i=si[r0], a1r=sr[r1], a1i=si[r1];
                sr[r0] = g0*a0r - g1*a0i + g2*a1r - g3*a1i;
                si[r0] = g0*a0i + g1*a0r + g2*a1i + g3*a1r;
                sr[r1] = g4*a0r - g5*a0i + g6*a1r - g7*a1i;
                si[r1] = g4*a0i + g5*a0r + g6*a1i + g7*a1r;
            }
        }
    }
}

// CNOT with control C, target T (qubit indices)
template<int C, int T>
__device__ __forceinline__ void cnot_g(float (&sr)[16], float (&si)[16], int ll)
{
    if constexpr (C < 4 && T < 4) {            // ctrl lane, tgt lane
        constexpr int LM = 1 << (3 - T);
        const int cb = (ll >> (3 - C)) & 1;
        #pragma unroll
        for (int r = 0; r < 16; ++r) {
            const float pr = lxor<LM>(sr[r]);
            const float pi = lxor<LM>(si[r]);
            sr[r] = cb ? pr : sr[r];
            si[r] = cb ? pi : si[r];
        }
    } else if constexpr (C < 4) {              // ctrl lane, tgt reg
        constexpr int TM = 1 << (7 - T);
        const int cb = (ll >> (3 - C)) & 1;
        #pragma unroll
        for (int r0 = 0; r0 < 16; ++r0) {
            if ((r0 & TM) == 0) {
                const int r1 = r0 | TM;
                const float t0r = sr[r0], t0i = si[r0];
                const float t1r = sr[r1], t1i = si[r1];
                sr[r0] = cb ? t1r : t0r;  si[r0] = cb ? t1i : t0i;
                sr[r1] = cb ? t0r : t1r;  si[r1] = cb ? t0i : t1i;
            }
        }
    } else if constexpr (T < 4) {              // ctrl reg, tgt lane
        constexpr int CM = 1 << (7 - C);
        constexpr int LM = 1 << (3 - T);
        #pragma unroll
        for (int r = 0; r < 16; ++r) {
            if (r & CM) {
                sr[r] = lxor<LM>(sr[r]);
                si[r] = lxor<LM>(si[r]);
            }
        }
    } else {                                   // ctrl reg, tgt reg: static swap
        constexpr int CM = 1 << (7 - C);
        constexpr int TM = 1 << (7 - T);
        #pragma unroll
        for (int r0 = 0; r0 < 16; ++r0) {
            if ((r0 & CM) && !(r0 & TM)) {
                const int r1 = r0 | TM;
                float t;
                t = sr[r0]; sr[r0] = sr[r1]; sr[r1] = t;
                t = si[r0]; si[r0] = si[r1]; si[r1] = t;
            }
        }
    }
}

template<int L>
__device__ __forceinline__ void rot_layer(float (&sr)[16], float (&si)[16],
                                          const float (*G)[8], int ll)
{
    rot_g<0>(sr, si, G[L*8+0], ll);
    rot_g<1>(sr, si, G[L*8+1], ll);
    rot_g<2>(sr, si, G[L*8+2], ll);
    rot_g<3>(sr, si, G[L*8+3], ll);
    rot_g<4>(sr, si, G[L*8+4], ll);
    rot_g<5>(sr, si, G[L*8+5], ll);
    rot_g<6>(sr, si, G[L*8+6], ll);
    rot_g<7>(sr, si, G[L*8+7], ll);
}

template<int L>
__device__ __forceinline__ void cnot_layer(float (&sr)[16], float (&si)[16], int ll)
{
    cnot_g<0, (0+L+1)%8>(sr, si, ll);
    cnot_g<1, (1+L+1)%8>(sr, si, ll);
    cnot_g<2, (2+L+1)%8>(sr, si, ll);
    cnot_g<3, (3+L+1)%8>(sr, si, ll);
    cnot_g<4, (4+L+1)%8>(sr, si, ll);
    cnot_g<5, (5+L+1)%8>(sr, si, ll);
    cnot_g<6, (6+L+1)%8>(sr, si, ll);
    cnot_g<7, (7+L+1)%8>(sr, si, ll);
}

__global__ void __launch_bounds__(256)
qae_fused(const float* __restrict__ x, const float* __restrict__ qw,
          const float* __restrict__ w1, const float* __restrict__ b1,
          const float* __restrict__ w2, const float* __restrict__ b2,
          float* __restrict__ out, int nsamp)
{
    __shared__ __align__(16) float G[32][8];
    const int tid = threadIdx.x;

    // Precompute the 32 shared Rot matrices once per block (broadcast via LDS).
    if (tid < 32) {
        const float phi = qw[tid*3+0], th = qw[tid*3+1], om = qw[tid*3+2];
        float s, c, sp, cp, sm, cm;
        sincosf(0.5f*th,       &s,  &c);
        sincosf(0.5f*(phi+om), &sp, &cp);
        sincosf(0.5f*(phi-om), &sm, &cm);
        G[tid][0] =  cp*c; G[tid][1] = -sp*c;   // m00
        G[tid][2] = -cm*s; G[tid][3] = -sm*s;   // m01
        G[tid][4] =  cm*s; G[tid][5] = -sm*s;   // m10
        G[tid][6] =  cp*c; G[tid][7] =  sp*c;   // m11
    }
    __syncthreads();

    const int gthread = blockIdx.x * 256 + tid;
    const int sample  = gthread >> 4;
    if (sample >= nsamp) return;
    const int ll = tid & 15;

    // --- init: product state  (Rot_rep0_i · RX(x_i)) |0>  per qubit ---
    // RX(x)|0> = (cos(x/2), -i sin(x/2));  w = M_rot · that.
    float w0r[8], w0i[8], w1r_[8], w1i_[8];
    #pragma unroll
    for (int i = 0; i < 8; ++i) {
        float sx, cx;
        __sincosf(0.5f * x[sample*8 + i], &sx, &cx);
        const float* g = G[i];   // rep 0, qubit i
        w0r[i]  = g[0]*cx + g[3]*sx;
        w0i[i]  = g[1]*cx - g[2]*sx;
        w1r_[i] = g[4]*cx + g[7]*sx;
        w1i_[i] = g[5]*cx - g[6]*sx;
    }

    // lane-part product over qubits 0..3
    float Lr = 1.f, Li = 0.f;
    #pragma unroll
    for (int i = 0; i < 4; ++i) {
        const int b = (ll >> (3 - i)) & 1;
        const float fr = b ? w1r_[i] : w0r[i];
        const float fi = b ? w1i_[i] : w0i[i];
        const float nr = Lr*fr - Li*fi;
        const float ni = Lr*fi + Li*fr;
        Lr = nr; Li = ni;
    }

    // reg-part product tree over qubits 4..7
    float p45r[4], p45i[4], p67r[4], p67i[4];
    #pragma unroll
    for (int a = 0; a < 4; ++a) {
        const int bh = (a >> 1) & 1, bl = a & 1;
        const float f4r = bh ? w1r_[4] : w0r[4], f4i = bh ? w1i_[4] : w0i[4];
        const float f5r = bl ? w1r_[5] : w0r[5], f5i = bl ? w1i_[5] : w0i[5];
        p45r[a] = f4r*f5r - f4i*f5i;
        p45i[a] = f4r*f5i + f4i*f5r;
        const float f6r = bh ? w1r_[6] : w0r[6], f6i = bh ? w1i_[6] : w0i[6];
        const float f7r = bl ? w1r_[7] : w0r[7], f7i = bl ? w1i_[7] : w0i[7];
        p67r[a] = f6r*f7r - f6i*f7i;
        p67i[a] = f6r*f7i + f6i*f7r;
    }
    float L45r[4], L45i[4];
    #pragma unroll
    for (int a = 0; a < 4; ++a) {
        L45r[a] = Lr*p45r[a] - Li*p45i[a];
        L45i[a] = Lr*p45i[a] + Li*p45r[a];
    }
    float sr[16], si[16];
    #pragma unroll
    for (int r = 0; r < 16; ++r) {
        const int a = r >> 2, b = r & 3;
        sr[r] = L45r[a]*p67r[b] - L45i[a]*p67i[b];
        si[r] = L45r[a]*p67i[b] + L45i[a]*p67r[b];
    }

    // --- circuit: rep0 Rot already folded into init ---
    cnot_layer<0>(sr, si, ll);
    rot_layer<1>(sr, si, G, ll);
    cnot_layer<1>(sr, si, ll);
    rot_layer<2>(sr, si, G, ll);
    cnot_layer<2>(sr, si, ll);
    rot_layer<3>(sr, si, G, ll);
    cnot_layer<3>(sr, si, ll);

    // --- readout: z_q = P(bit_q=0) - P(bit_q=1) ---
    float z[8];
    float ptot = 0.f;
    z[4] = 0.f; z[5] = 0.f; z[6] = 0.f; z[7] = 0.f;
    #pragma unroll
    for (int r = 0; r < 16; ++r) {
        const float p = sr[r]*sr[r] + si[r]*si[r];
        ptot += p;
        z[4] += (r & 8) ? -p : p;
        z[5] += (r & 4) ? -p : p;
        z[6] += (r & 2) ? -p : p;
        z[7] += (r & 1) ? -p : p;
    }
    #pragma unroll
    for (int q = 0; q < 4; ++q)
        z[q] = ((ll >> (3 - q)) & 1) ? -ptot : ptot;

    // reduce over the 16-lane group (all lanes end with the full sums)
    #pragma unroll
    for (int q = 0; q < 8; ++q) z[q] += lxor<1>(z[q]);
    #pragma unroll
    for (int q = 0; q < 8; ++q) z[q] += lxor<2>(z[q]);
    #pragma unroll
    for (int q = 0; q < 8; ++q) z[q] += lxor<4>(z[q]);
    #pragma unroll
    for (int q = 0; q < 8; ++q) z[q] += lxor<8>(z[q]);

    // --- MLP: out = w2 · relu(w1 · z + b1) + b2 ---
    if (ll < 8) {
        float h0 = b1[0], h1 = b1[1], h2 = b1[2], h3 = b1[3];
        #pragma unroll
        for (int i = 0; i < 8; ++i) {
            h0 += z[i] * w1[i];
            h1 += z[i] * w1[8 + i];
            h2 += z[i] * w1[16 + i];
            h3 += z[i] * w1[24 + i];
        }
        h0 = fmaxf(h0, 0.f); h1 = fmaxf(h1, 0.f);
        h2 = fmaxf(h2, 0.f); h3 = fmaxf(h3, 0.f);
        const float o = b2[ll] + h0*w2[ll*4+0] + h1*w2[ll*4+1]
                                + h2*w2[ll*4+2] + h3*w2[ll*4+3];
        out[sample*8 + ll] = o;
    }
}

extern "C" void kernel_launch(void* const* d_in, const int* in_sizes, int n_in,
                              void* d_out, int out_size, void* d_ws, size_t ws_size,
                              hipStream_t stream)
{
    const float* x  = (const float*)d_in[0];
    const float* qw = (const float*)d_in[1];
    const float* w1 = (const float*)d_in[2];
    const float* b1 = (const float*)d_in[3];
    const float* w2 = (const float*)d_in[4];
    const float* b2 = (const float*)d_in[5];
    float* out = (float*)d_out;

    const int nsamp = in_sizes[0] / 8;          // 65536
    const int total_threads = nsamp * 16;       // 16 lanes per sample
    const int blocks = (total_threads + 255) / 256;

    hipLaunchKernelGGL(qae_fused, dim3(blocks), dim3(256), 0, stream,
                       x, qw, w1, b1, w2, b2, out, nsamp);
}

// Round 3
// 97.476 us; speedup vs baseline: 1.8172x; 1.8172x over previous
//
#include <hip/hip_runtime.h>
#include <math.h>

// Layout: sample = 16 lanes x 16 register slots = 256 amplitudes.
// Qubit q in 0..3  -> lane bit  (3-q) of (tid & 15)   (lane xor mask 1<<(3-q))
// Qubit q in 4..7  -> slot bit  (7-q) of r            (reg mask 1<<(7-q))
// State amp packed v2f = (re, im).
// Gate constants per matrix entry m: A = (m.re, m.re), B = (-m.im, m.im), so
//   m * s  ==  A ⊙ s  +  B ⊙ swap(s)      (⊙ = elementwise packed fp32)
// -> complex MAC needs NO asm modifiers; compiler emits v_pk_fma_f32.

typedef float v2f __attribute__((ext_vector_type(2)));

// ---- cross-lane xor within 16-lane rows (round-1-verified primitives) ----
template<int CTRL>
__device__ __forceinline__ float dppf(float v) {
    const int i = __float_as_int(v);
    return __int_as_float(__builtin_amdgcn_update_dpp(i, i, CTRL, 0xF, 0xF, true));
}
template<int M>
__device__ __forceinline__ float lxorf(float v) {
    static_assert(M == 1 || M == 2 || M == 4 || M == 8, "bad mask");
    if constexpr (M == 1)      return dppf<0xB1>(v);   // quad_perm [1,0,3,2]
    else if constexpr (M == 2) return dppf<0x4E>(v);   // quad_perm [2,3,0,1]
    else if constexpr (M == 4) return __int_as_float(__builtin_amdgcn_ds_swizzle(__float_as_int(v), 0x101F));
    else                       return __int_as_float(__builtin_amdgcn_ds_swizzle(__float_as_int(v), 0x201F));
}
template<int M>
__device__ __forceinline__ v2f lxor2(v2f v) {
    v2f r; r.x = lxorf<M>(v.x); r.y = lxorf<M>(v.y); return r;
}

// ---- packed helpers (compiler-generated VOP3P, no inline asm) ----
__device__ __forceinline__ v2f sw2(v2f v)                 { return __builtin_shufflevector(v, v, 1, 0); }
__device__ __forceinline__ v2f pkfma(v2f a, v2f b, v2f c) { return __builtin_elementwise_fma(a, b, c); }
// scalar-style complex multiply (used in the small init tree)
__device__ __forceinline__ v2f cmul_s(v2f a, v2f b) {
    v2f d;
    d.x = fmaf(a.x, b.x, -(a.y * b.y));
    d.y = fmaf(a.x, b.y,  (a.y * b.x));
    return d;
}

// ---------------- gates ----------------
// Rot on qubit Q; A[e]=(m_e.re,m_e.re), B[e]=(-m_e.im,m_e.im), e = {00,01,10,11}
template<int Q>
__device__ __forceinline__ void rot_g(v2f (&s)[16], const v2f (&A)[4], const v2f (&B)[4], int ll)
{
    if constexpr (Q < 4) {
        constexpr int LM = 1 << (3 - Q);
        const bool hi = (ll >> (3 - Q)) & 1;
        const v2f Aa = hi ? A[3] : A[0], Ba = hi ? B[3] : B[0];   // coeff on my amp
        const v2f Ab = hi ? A[2] : A[1], Bb = hi ? B[2] : B[1];   // coeff on partner
        #pragma unroll
        for (int r = 0; r < 16; ++r) {
            const v2f m = s[r];
            v2f p; p.x = lxorf<LM>(m.x); p.y = lxorf<LM>(m.y);
            const v2f ms = sw2(m), ps = sw2(p);
            s[r] = pkfma(Aa, m, pkfma(Ba, ms, pkfma(Ab, p, Bb * ps)));
        }
    } else {
        constexpr int RM = 1 << (7 - Q);
        #pragma unroll
        for (int r0 = 0; r0 < 16; ++r0) {
            if ((r0 & RM) == 0) {
                const int r1 = r0 | RM;
                const v2f a0 = s[r0], a1 = s[r1];
                const v2f a0s = sw2(a0), a1s = sw2(a1);
                s[r0] = pkfma(A[0], a0, pkfma(B[0], a0s, pkfma(A[1], a1, B[1] * a1s)));
                s[r1] = pkfma(A[2], a0, pkfma(B[2], a0s, pkfma(A[3], a1, B[3] * a1s)));
            }
        }
    }
}

template<int C, int T>
__device__ __forceinline__ void cnot_g(v2f (&s)[16], int ll)
{
    if constexpr (C < 4 && T < 4) {            // ctrl lane, tgt lane
        constexpr int LM = 1 << (3 - T);
        const bool cb = (ll >> (3 - C)) & 1;
        #pragma unroll
        for (int r = 0; r < 16; ++r) {
            const v2f p = lxor2<LM>(s[r]);
            s[r] = cb ? p : s[r];
        }
    } else if constexpr (C < 4) {              // ctrl lane, tgt reg
        constexpr int TM = 1 << (7 - T);
        const bool cb = (ll >> (3 - C)) & 1;
        #pragma unroll
        for (int r0 = 0; r0 < 16; ++r0) {
            if ((r0 & TM) == 0) {
                const int r1 = r0 | TM;
                const v2f t0 = s[r0], t1 = s[r1];
                s[r0] = cb ? t1 : t0;
                s[r1] = cb ? t0 : t1;
            }
        }
    } else if constexpr (T < 4) {              // ctrl reg, tgt lane
        constexpr int CM = 1 << (7 - C);
        constexpr int LM = 1 << (3 - T);
        #pragma unroll
        for (int r = 0; r < 16; ++r) {
            if (r & CM) s[r] = lxor2<LM>(s[r]);
        }
    } else {                                   // ctrl reg, tgt reg: free rename
        constexpr int CM = 1 << (7 - C);
        constexpr int TM = 1 << (7 - T);
        #pragma unroll
        for (int r0 = 0; r0 < 16; ++r0) {
            if ((r0 & CM) && !(r0 & TM)) {
                const int r1 = r0 | TM;
                const v2f t = s[r0]; s[r0] = s[r1]; s[r1] = t;
            }
        }
    }
}

template<int L>
__device__ __forceinline__ void rot_layer(v2f (&s)[16],
                                          const v2f (*Ga)[4], const v2f (*Gb)[4], int ll)
{
    #pragma unroll
    for (int i = 0; i < 8; ++i) {
        v2f A[4], B[4];
        #pragma unroll
        for (int e = 0; e < 4; ++e) { A[e] = Ga[L*8+i][e]; B[e] = Gb[L*8+i][e]; }
        switch (i) {
            case 0: rot_g<0>(s, A, B, ll); break;
            case 1: rot_g<1>(s, A, B, ll); break;
            case 2: rot_g<2>(s, A, B, ll); break;
            case 3: rot_g<3>(s, A, B, ll); break;
            case 4: rot_g<4>(s, A, B, ll); break;
            case 5: rot_g<5>(s, A, B, ll); break;
            case 6: rot_g<6>(s, A, B, ll); break;
            case 7: rot_g<7>(s, A, B, ll); break;
        }
    }
}

template<int L>
__device__ __forceinline__ void cnot_layer(v2f (&s)[16], int ll)
{
    cnot_g<0, (0+L+1)%8>(s, ll);
    cnot_g<1, (1+L+1)%8>(s, ll);
    cnot_g<2, (2+L+1)%8>(s, ll);
    cnot_g<3, (3+L+1)%8>(s, ll);
    cnot_g<4, (4+L+1)%8>(s, ll);
    cnot_g<5, (5+L+1)%8>(s, ll);
    cnot_g<6, (6+L+1)%8>(s, ll);
    cnot_g<7, (7+L+1)%8>(s, ll);
}

__global__ void __launch_bounds__(256)
qae_fused(const float* __restrict__ x, const float* __restrict__ qw,
          const float* __restrict__ w1, const float* __restrict__ b1,
          const float* __restrict__ w2, const float* __restrict__ b2,
          float* __restrict__ out, int nsamp)
{
    __shared__ __align__(16) v2f Ga[32][4];   // (re, re) per entry
    __shared__ __align__(16) v2f Gb[32][4];   // (-im, im) per entry
    __shared__ __align__(16) v2f Gc[8][4];    // plain complex, rep-0 gates (init)
    const int tid = threadIdx.x;

    if (tid < 32) {
        const float phi = qw[tid*3+0], th = qw[tid*3+1], om = qw[tid*3+2];
        float s, c, sp, cp, sm, cm;
        sincosf(0.5f*th,       &s,  &c);
        sincosf(0.5f*(phi+om), &sp, &cp);
        sincosf(0.5f*(phi-om), &sm, &cm);
        const float m00r =  cp*c, m00i = -sp*c;
        const float m01r = -cm*s, m01i = -sm*s;
        const float m10r =  cm*s, m10i = -sm*s;
        const float m11r =  cp*c, m11i =  sp*c;
        v2f t;
        t.x = m00r; t.y = m00r; Ga[tid][0] = t;
        t.x = m01r; t.y = m01r; Ga[tid][1] = t;
        t.x = m10r; t.y = m10r; Ga[tid][2] = t;
        t.x = m11r; t.y = m11r; Ga[tid][3] = t;
        t.x = -m00i; t.y = m00i; Gb[tid][0] = t;
        t.x = -m01i; t.y = m01i; Gb[tid][1] = t;
        t.x = -m10i; t.y = m10i; Gb[tid][2] = t;
        t.x = -m11i; t.y = m11i; Gb[tid][3] = t;
        if (tid < 8) {
            t.x = m00r; t.y = m00i; Gc[tid][0] = t;
            t.x = m01r; t.y = m01i; Gc[tid][1] = t;
            t.x = m10r; t.y = m10i; Gc[tid][2] = t;
            t.x = m11r; t.y = m11i; Gc[tid][3] = t;
        }
    }
    __syncthreads();

    const int gthread = blockIdx.x * 256 + tid;
    const int sample  = gthread >> 4;
    if (sample >= nsamp) return;
    const int ll = tid & 15;
    const int b0 = (ll >> 3) & 1, b1_ = (ll >> 2) & 1, b2_ = (ll >> 1) & 1, b3 = ll & 1;

    // --- init: product state  (Rot_rep0_i · RX(x_i)) |0>  per qubit (scalar, r1-verified) ---
    const float4 xv0 = *reinterpret_cast<const float4*>(x + sample*8);
    const float4 xv1 = *reinterpret_cast<const float4*>(x + sample*8 + 4);
    const float xs[8] = {xv0.x, xv0.y, xv0.z, xv0.w, xv1.x, xv1.y, xv1.z, xv1.w};

    v2f w0v[8], w1v[8];
    #pragma unroll
    for (int i = 0; i < 8; ++i) {
        float sx, cx;
        __sincosf(0.5f * xs[i], &sx, &cx);
        const v2f m00 = Gc[i][0], m01 = Gc[i][1], m10 = Gc[i][2], m11 = Gc[i][3];
        // w0 = cx*m00 + sx*(m01.im, -m01.re);  w1 = cx*m10 + sx*(m11.im, -m11.re)
        w0v[i].x = fmaf(cx, m00.x,  sx * m01.y);
        w0v[i].y = fmaf(cx, m00.y, -(sx * m01.x));
        w1v[i].x = fmaf(cx, m10.x,  sx * m11.y);
        w1v[i].y = fmaf(cx, m10.y, -(sx * m11.x));
    }

    // lane-part product over qubits 0..3
    v2f L = b0 ? w1v[0] : w0v[0];
    L = cmul_s(L, b1_ ? w1v[1] : w0v[1]);
    L = cmul_s(L, b2_ ? w1v[2] : w0v[2]);
    L = cmul_s(L, b3  ? w1v[3] : w0v[3]);

    // reg-part product tree over qubits 4..7
    v2f p45[4], p67[4];
    #pragma unroll
    for (int a = 0; a < 4; ++a) {
        const int bh = (a >> 1) & 1, bl = a & 1;
        p45[a] = cmul_s(bh ? w1v[4] : w0v[4], bl ? w1v[5] : w0v[5]);
        p67[a] = cmul_s(bh ? w1v[6] : w0v[6], bl ? w1v[7] : w0v[7]);
    }
    v2f L45[4];
    #pragma unroll
    for (int a = 0; a < 4; ++a) L45[a] = cmul_s(L, p45[a]);

    v2f s[16];
    #pragma unroll
    for (int r = 0; r < 16; ++r) s[r] = cmul_s(L45[r >> 2], p67[r & 3]);

    // --- circuit: rep0 Rot folded into init ---
    cnot_layer<0>(s, ll);
    rot_layer<1>(s, Ga, Gb, ll);
    cnot_layer<1>(s, ll);
    rot_layer<2>(s, Ga, Gb, ll);
    cnot_layer<2>(s, ll);
    rot_layer<3>(s, Ga, Gb, ll);
    cnot_layer<3>(s, ll);

    // --- readout: per-slot probabilities, then WHT tree ---
    float p[16];
    #pragma unroll
    for (int r = 0; r < 16; ++r) {
        const v2f q = s[r] * s[r];
        p[r] = q.x + q.y;
    }
    // qubit7 <-> bit0 of r, qubit6 <-> bit1, qubit5 <-> bit2, qubit4 <-> bit3
    float s1[8]; float z7 = 0.f;
    #pragma unroll
    for (int i = 0; i < 8; ++i) { s1[i] = p[2*i] + p[2*i+1]; z7 += p[2*i] - p[2*i+1]; }
    float s2[4]; float z6 = 0.f;
    #pragma unroll
    for (int i = 0; i < 4; ++i) { s2[i] = s1[2*i] + s1[2*i+1]; z6 += s1[2*i] - s1[2*i+1]; }
    const float s30 = s2[0] + s2[1], s31 = s2[2] + s2[3];
    const float z5  = (s2[0] - s2[1]) + (s2[2] - s2[3]);
    const float ptot = s30 + s31;
    const float z4   = s30 - s31;

    float z[8];
    const float npt = -ptot;
    z[0] = b0  ? npt : ptot;
    z[1] = b1_ ? npt : ptot;
    z[2] = b2_ ? npt : ptot;
    z[3] = b3  ? npt : ptot;
    z[4] = z4; z[5] = z5; z[6] = z6; z[7] = z7;

    // reduce over the 16-lane group (r1-verified primitives)
    #pragma unroll
    for (int q = 0; q < 8; ++q) z[q] += lxorf<1>(z[q]);
    #pragma unroll
    for (int q = 0; q < 8; ++q) z[q] += lxorf<2>(z[q]);
    #pragma unroll
    for (int q = 0; q < 8; ++q) z[q] += lxorf<4>(z[q]);
    #pragma unroll
    for (int q = 0; q < 8; ++q) z[q] += lxorf<8>(z[q]);

    // --- MLP: out = w2 · relu(w1 · z + b1) + b2 ---
    if (ll < 8) {
        float h0 = b1[0], h1 = b1[1], h2 = b1[2], h3 = b1[3];
        #pragma unroll
        for (int i = 0; i < 8; ++i) {
            h0 += z[i] * w1[i];
            h1 += z[i] * w1[8 + i];
            h2 += z[i] * w1[16 + i];
            h3 += z[i] * w1[24 + i];
        }
        h0 = fmaxf(h0, 0.f); h1 = fmaxf(h1, 0.f);
        h2 = fmaxf(h2, 0.f); h3 = fmaxf(h3, 0.f);
        const float o = b2[ll] + h0*w2[ll*4+0] + h1*w2[ll*4+1]
                                + h2*w2[ll*4+2] + h3*w2[ll*4+3];
        out[sample*8 + ll] = o;
    }
}

extern "C" void kernel_launch(void* const* d_in, const int* in_sizes, int n_in,
                              void* d_out, int out_size, void* d_ws, size_t ws_size,
                              hipStream_t stream)
{
    const float* x  = (const float*)d_in[0];
    const float* qw = (const float*)d_in[1];
    const float* w1 = (const float*)d_in[2];
    const float* b1 = (const float*)d_in[3];
    const float* w2 = (const float*)d_in[4];
    const float* b2 = (const float*)d_in[5];
    float* out = (float*)d_out;

    const int nsamp = in_sizes[0] / 8;          // 65536
    const int total_threads = nsamp * 16;       // 16 lanes per sample
    const int blocks = (total_threads + 255) / 256;

    hipLaunchKernelGGL(qae_fused, dim3(blocks), dim3(256), 0, stream,
                       x, qw, w1, b1, w2, b2, out, nsamp);
}

// Round 4
// 93.831 us; speedup vs baseline: 1.8878x; 1.0389x over previous
//
#include <hip/hip_runtime.h>
#include <math.h>

// Layout: sample = 16 lanes x 16 register slots = 256 amplitudes; 2 samples/thread.
// Qubit q in 0..3  -> lane bit  (3-q) of (tid & 15)   (lane xor mask 1<<(3-q))
// Qubit q in 4..7  -> slot bit  (7-q) of r            (reg mask 1<<(7-q))
// State amp packed v2f = (re, im).
// Gate constants per matrix entry m: A = (m.re, m.re), B = (-m.im, m.im):
//   m * s == A ⊙ s + B ⊙ swap(s)   (compiler emits v_pk_fma_f32, no asm modifiers)
// Final CNOT layer (r=4) is folded into readout sign masks:
//   V0..V3 = v4..v7 ; V4..V7 = v0^v4 .. v3^v7
//   => z0..3 = allreduce(S8,S4,S2,S1), z4..7 = lane-signed reduce of the same S's,
//   where Sm = sum_r sign(r&m) p[r].

typedef float v2f __attribute__((ext_vector_type(2)));

// ---- cross-lane xor within 16-lane rows (round-1/3-verified primitives) ----
template<int CTRL>
__device__ __forceinline__ float dppf(float v) {
    const int i = __float_as_int(v);
    return __int_as_float(__builtin_amdgcn_update_dpp(i, i, CTRL, 0xF, 0xF, true));
}
template<int M>
__device__ __forceinline__ float lxorf(float v) {
    static_assert(M == 1 || M == 2 || M == 4 || M == 8, "bad mask");
    if constexpr (M == 1)      return dppf<0xB1>(v);   // quad_perm [1,0,3,2]
    else if constexpr (M == 2) return dppf<0x4E>(v);   // quad_perm [2,3,0,1]
    else if constexpr (M == 4) return __int_as_float(__builtin_amdgcn_ds_swizzle(__float_as_int(v), 0x101F));
    else                       return __int_as_float(__builtin_amdgcn_ds_swizzle(__float_as_int(v), 0x201F));
}
template<int M>
__device__ __forceinline__ v2f lxor2(v2f v) {
    v2f r; r.x = lxorf<M>(v.x); r.y = lxorf<M>(v.y); return r;
}

__device__ __forceinline__ v2f sw2(v2f v)                 { return __builtin_shufflevector(v, v, 1, 0); }
__device__ __forceinline__ v2f pkfma(v2f a, v2f b, v2f c) { return __builtin_elementwise_fma(a, b, c); }
__device__ __forceinline__ v2f cmul_s(v2f a, v2f b) {
    v2f d;
    d.x = fmaf(a.x, b.x, -(a.y * b.y));
    d.y = fmaf(a.x, b.y,  (a.y * b.x));
    return d;
}

// ---------------- gates (two states per call) ----------------
template<int Q>
__device__ __forceinline__ void rot_g2(v2f (&sa)[16], v2f (&sb)[16],
                                       const v2f (&A)[4], const v2f (&B)[4], int ll)
{
    if constexpr (Q < 4) {
        constexpr int LM = 1 << (3 - Q);
        const bool hi = (ll >> (3 - Q)) & 1;
        const v2f Aa = hi ? A[3] : A[0], Ba = hi ? B[3] : B[0];
        const v2f Ab = hi ? A[2] : A[1], Bb = hi ? B[2] : B[1];
        #pragma unroll
        for (int r = 0; r < 16; ++r) {
            const v2f ma = sa[r], mb = sb[r];
            v2f pa, pb;
            pa.x = lxorf<LM>(ma.x); pa.y = lxorf<LM>(ma.y);
            pb.x = lxorf<LM>(mb.x); pb.y = lxorf<LM>(mb.y);
            sa[r] = pkfma(Aa, ma, pkfma(Ba, sw2(ma), pkfma(Ab, pa, Bb * sw2(pa))));
            sb[r] = pkfma(Aa, mb, pkfma(Ba, sw2(mb), pkfma(Ab, pb, Bb * sw2(pb))));
        }
    } else {
        constexpr int RM = 1 << (7 - Q);
        #pragma unroll
        for (int r0 = 0; r0 < 16; ++r0) {
            if ((r0 & RM) == 0) {
                const int r1 = r0 | RM;
                {
                    const v2f a0 = sa[r0], a1 = sa[r1];
                    sa[r0] = pkfma(A[0], a0, pkfma(B[0], sw2(a0), pkfma(A[1], a1, B[1] * sw2(a1))));
                    sa[r1] = pkfma(A[2], a0, pkfma(B[2], sw2(a0), pkfma(A[3], a1, B[3] * sw2(a1))));
                }
                {
                    const v2f a0 = sb[r0], a1 = sb[r1];
                    sb[r0] = pkfma(A[0], a0, pkfma(B[0], sw2(a0), pkfma(A[1], a1, B[1] * sw2(a1))));
                    sb[r1] = pkfma(A[2], a0, pkfma(B[2], sw2(a0), pkfma(A[3], a1, B[3] * sw2(a1))));
                }
            }
        }
    }
}

template<int C, int T>
__device__ __forceinline__ void cnot_g(v2f (&s)[16], int ll)
{
    if constexpr (C < 4 && T < 4) {            // ctrl lane, tgt lane
        constexpr int LM = 1 << (3 - T);
        const bool cb = (ll >> (3 - C)) & 1;
        #pragma unroll
        for (int r = 0; r < 16; ++r) {
            const v2f p = lxor2<LM>(s[r]);
            s[r] = cb ? p : s[r];
        }
    } else if constexpr (C < 4) {              // ctrl lane, tgt reg
        constexpr int TM = 1 << (7 - T);
        const bool cb = (ll >> (3 - C)) & 1;
        #pragma unroll
        for (int r0 = 0; r0 < 16; ++r0) {
            if ((r0 & TM) == 0) {
                const int r1 = r0 | TM;
                const v2f t0 = s[r0], t1 = s[r1];
                s[r0] = cb ? t1 : t0;
                s[r1] = cb ? t0 : t1;
            }
        }
    } else if constexpr (T < 4) {              // ctrl reg, tgt lane
        constexpr int CM = 1 << (7 - C);
        constexpr int LM = 1 << (3 - T);
        #pragma unroll
        for (int r = 0; r < 16; ++r) {
            if (r & CM) s[r] = lxor2<LM>(s[r]);
        }
    } else {                                   // ctrl reg, tgt reg: free rename
        constexpr int CM = 1 << (7 - C);
        constexpr int TM = 1 << (7 - T);
        #pragma unroll
        for (int r0 = 0; r0 < 16; ++r0) {
            if ((r0 & CM) && !(r0 & TM)) {
                const int r1 = r0 | TM;
                const v2f t = s[r0]; s[r0] = s[r1]; s[r1] = t;
            }
        }
    }
}

template<int L>
__device__ __forceinline__ void rot_layer2(v2f (&sa)[16], v2f (&sb)[16],
                                           const v2f (*Ga)[4], const v2f (*Gb)[4], int ll)
{
    #pragma unroll
    for (int i = 0; i < 8; ++i) {
        v2f A[4], B[4];
        #pragma unroll
        for (int e = 0; e < 4; ++e) { A[e] = Ga[L*8+i][e]; B[e] = Gb[L*8+i][e]; }
        switch (i) {
            case 0: rot_g2<0>(sa, sb, A, B, ll); break;
            case 1: rot_g2<1>(sa, sb, A, B, ll); break;
            case 2: rot_g2<2>(sa, sb, A, B, ll); break;
            case 3: rot_g2<3>(sa, sb, A, B, ll); break;
            case 4: rot_g2<4>(sa, sb, A, B, ll); break;
            case 5: rot_g2<5>(sa, sb, A, B, ll); break;
            case 6: rot_g2<6>(sa, sb, A, B, ll); break;
            case 7: rot_g2<7>(sa, sb, A, B, ll); break;
        }
    }
}

template<int L>
__device__ __forceinline__ void cnot_layer2(v2f (&sa)[16], v2f (&sb)[16], int ll)
{
    cnot_g<0, (0+L+1)%8>(sa, ll); cnot_g<0, (0+L+1)%8>(sb, ll);
    cnot_g<1, (1+L+1)%8>(sa, ll); cnot_g<1, (1+L+1)%8>(sb, ll);
    cnot_g<2, (2+L+1)%8>(sa, ll); cnot_g<2, (2+L+1)%8>(sb, ll);
    cnot_g<3, (3+L+1)%8>(sa, ll); cnot_g<3, (3+L+1)%8>(sb, ll);
    cnot_g<4, (4+L+1)%8>(sa, ll); cnot_g<4, (4+L+1)%8>(sb, ll);
    cnot_g<5, (5+L+1)%8>(sa, ll); cnot_g<5, (5+L+1)%8>(sb, ll);
    cnot_g<6, (6+L+1)%8>(sa, ll); cnot_g<6, (6+L+1)%8>(sb, ll);
    cnot_g<7, (7+L+1)%8>(sa, ll); cnot_g<7, (7+L+1)%8>(sb, ll);
}

// --- init: product state (Rot_rep0_i · RX(x_i)) |0> (round-3-verified) ---
__device__ __forceinline__ void init_state(const float* __restrict__ xp,
                                           const v2f (*Gc)[4], int ll, v2f (&s)[16])
{
    const float4 xv0 = *reinterpret_cast<const float4*>(xp);
    const float4 xv1 = *reinterpret_cast<const float4*>(xp + 4);
    const float xs[8] = {xv0.x, xv0.y, xv0.z, xv0.w, xv1.x, xv1.y, xv1.z, xv1.w};
    const int b0 = (ll >> 3) & 1, b1_ = (ll >> 2) & 1, b2_ = (ll >> 1) & 1, b3 = ll & 1;

    v2f w0v[8], w1v[8];
    #pragma unroll
    for (int i = 0; i < 8; ++i) {
        float sx, cx;
        __sincosf(0.5f * xs[i], &sx, &cx);
        const v2f m00 = Gc[i][0], m01 = Gc[i][1], m10 = Gc[i][2], m11 = Gc[i][3];
        w0v[i].x = fmaf(cx, m00.x,  sx * m01.y);
        w0v[i].y = fmaf(cx, m00.y, -(sx * m01.x));
        w1v[i].x = fmaf(cx, m10.x,  sx * m11.y);
        w1v[i].y = fmaf(cx, m10.y, -(sx * m11.x));
    }

    v2f L = b0 ? w1v[0] : w0v[0];
    L = cmul_s(L, b1_ ? w1v[1] : w0v[1]);
    L = cmul_s(L, b2_ ? w1v[2] : w0v[2]);
    L = cmul_s(L, b3  ? w1v[3] : w0v[3]);

    v2f p45[4], p67[4];
    #pragma unroll
    for (int a = 0; a < 4; ++a) {
        const int bh = (a >> 1) & 1, bl = a & 1;
        p45[a] = cmul_s(bh ? w1v[4] : w0v[4], bl ? w1v[5] : w0v[5]);
        p67[a] = cmul_s(bh ? w1v[6] : w0v[6], bl ? w1v[7] : w0v[7]);
    }
    v2f L45[4];
    #pragma unroll
    for (int a = 0; a < 4; ++a) L45[a] = cmul_s(L, p45[a]);
    #pragma unroll
    for (int r = 0; r < 16; ++r) s[r] = cmul_s(L45[r >> 2], p67[r & 3]);
}

// --- slot-space signed sums Sm = sum_r sign(r&m) p[r] ---
__device__ __forceinline__ void slot_wht(const v2f (&s)[16],
                                         float& S1, float& S2, float& S4, float& S8)
{
    float p[16];
    #pragma unroll
    for (int r = 0; r < 16; ++r) {
        const v2f q = s[r] * s[r];
        p[r] = q.x + q.y;
    }
    float e[8]; S1 = 0.f;
    #pragma unroll
    for (int i = 0; i < 8; ++i) { e[i] = p[2*i] + p[2*i+1]; S1 += p[2*i] - p[2*i+1]; }
    float f[4]; S2 = 0.f;
    #pragma unroll
    for (int i = 0; i < 4; ++i) { f[i] = e[2*i] + e[2*i+1]; S2 += e[2*i] - e[2*i+1]; }
    S4 = (f[0] - f[1]) + (f[2] - f[3]);
    S8 = (f[0] + f[1]) - (f[2] + f[3]);
}

// --- 16-lane butterfly: zp = sum_ll S ; zs = sum_ll sign(ll&M) S ---
template<int M>
__device__ __forceinline__ void bfly(float S, int ll, float& zp, float& zs)
{
    float v = S;
    if constexpr (M != 1) v += lxorf<1>(v);
    if constexpr (M != 2) v += lxorf<2>(v);
    if constexpr (M != 4) v += lxorf<4>(v);
    if constexpr (M != 8) v += lxorf<8>(v);
    const float t = lxorf<M>(v);
    zp = v + t;
    const float d = v - t;
    zs = (ll & M) ? -d : d;
}

__global__ void __launch_bounds__(256, 2)
qae_fused(const float* __restrict__ x, const float* __restrict__ qw,
          const float* __restrict__ w1, const float* __restrict__ b1,
          const float* __restrict__ w2, const float* __restrict__ b2,
          float* __restrict__ out, int nsamp)
{
    __shared__ __align__(16) v2f Ga[32][4];   // (re, re) per entry
    __shared__ __align__(16) v2f Gb[32][4];   // (-im, im) per entry
    __shared__ __align__(16) v2f Gc[8][4];    // plain complex, rep-0 gates (init)
    const int tid = threadIdx.x;

    if (tid < 32) {
        const float phi = qw[tid*3+0], th = qw[tid*3+1], om = qw[tid*3+2];
        float s, c, sp, cp, sm, cm;
        sincosf(0.5f*th,       &s,  &c);
        sincosf(0.5f*(phi+om), &sp, &cp);
        sincosf(0.5f*(phi-om), &sm, &cm);
        const float m00r =  cp*c, m00i = -sp*c;
        const float m01r = -cm*s, m01i = -sm*s;
        const float m10r =  cm*s, m10i = -sm*s;
        const float m11r =  cp*c, m11i =  sp*c;
        v2f t;
        t.x = m00r;  t.y = m00r; Ga[tid][0] = t;
        t.x = m01r;  t.y = m01r; Ga[tid][1] = t;
        t.x = m10r;  t.y = m10r; Ga[tid][2] = t;
        t.x = m11r;  t.y = m11r; Ga[tid][3] = t;
        t.x = -m00i; t.y = m00i; Gb[tid][0] = t;
        t.x = -m01i; t.y = m01i; Gb[tid][1] = t;
        t.x = -m10i; t.y = m10i; Gb[tid][2] = t;
        t.x = -m11i; t.y = m11i; Gb[tid][3] = t;
        if (tid < 8) {
            t.x = m00r; t.y = m00i; Gc[tid][0] = t;
            t.x = m01r; t.y = m01i; Gc[tid][1] = t;
            t.x = m10r; t.y = m10i; Gc[tid][2] = t;
            t.x = m11r; t.y = m11i; Gc[tid][3] = t;
        }
    }
    __syncthreads();

    const int group = (blockIdx.x * 256 + tid) >> 4;
    const int sA = group * 2;
    if (sA >= nsamp) return;
    const int ll = tid & 15;

    v2f sa[16], sb[16];
    init_state(x + (size_t)sA * 8,     Gc, ll, sa);
    init_state(x + (size_t)sA * 8 + 8, Gc, ll, sb);

    // --- circuit: rep0 Rot folded into init; final CNOT layer folded into readout ---
    cnot_layer2<0>(sa, sb, ll);
    rot_layer2<1>(sa, sb, Ga, Gb, ll);
    cnot_layer2<1>(sa, sb, ll);
    rot_layer2<2>(sa, sb, Ga, Gb, ll);
    cnot_layer2<2>(sa, sb, ll);
    rot_layer2<3>(sa, sb, Ga, Gb, ll);

    // --- readout with folded CNOT-layer-3 sign masks ---
    float S1a, S2a, S4a, S8a, S1b, S2b, S4b, S8b;
    slot_wht(sa, S1a, S2a, S4a, S8a);
    slot_wht(sb, S1b, S2b, S4b, S8b);

    float zA[8], zB[8];
    bfly<8>(S8a, ll, zA[0], zA[4]);
    bfly<4>(S4a, ll, zA[1], zA[5]);
    bfly<2>(S2a, ll, zA[2], zA[6]);
    bfly<1>(S1a, ll, zA[3], zA[7]);
    bfly<8>(S8b, ll, zB[0], zB[4]);
    bfly<4>(S4b, ll, zB[1], zB[5]);
    bfly<2>(S2b, ll, zB[2], zB[6]);
    bfly<1>(S1b, ll, zB[3], zB[7]);

    // lanes 0-7 handle sample A, lanes 8-15 handle sample B (all lanes active)
    float zs[8];
    #pragma unroll
    for (int i = 0; i < 8; ++i) zs[i] = (ll < 8) ? zA[i] : zB[i];

    // --- MLP: out = w2 · relu(w1 · z + b1) + b2 ---
    const int col = ll & 7;
    float h0 = b1[0], h1 = b1[1], h2 = b1[2], h3 = b1[3];
    #pragma unroll
    for (int i = 0; i < 8; ++i) {
        h0 += zs[i] * w1[i];
        h1 += zs[i] * w1[8 + i];
        h2 += zs[i] * w1[16 + i];
        h3 += zs[i] * w1[24 + i];
    }
    h0 = fmaxf(h0, 0.f); h1 = fmaxf(h1, 0.f);
    h2 = fmaxf(h2, 0.f); h3 = fmaxf(h3, 0.f);
    const float o = b2[col] + h0*w2[col*4+0] + h1*w2[col*4+1]
                            + h2*w2[col*4+2] + h3*w2[col*4+3];
    out[(size_t)(sA + (ll >> 3)) * 8 + col] = o;
}

extern "C" void kernel_launch(void* const* d_in, const int* in_sizes, int n_in,
                              void* d_out, int out_size, void* d_ws, size_t ws_size,
                              hipStream_t stream)
{
    const float* x  = (const float*)d_in[0];
    const float* qw = (const float*)d_in[1];
    const float* w1 = (const float*)d_in[2];
    const float* b1 = (const float*)d_in[3];
    const float* w2 = (const float*)d_in[4];
    const float* b2 = (const float*)d_in[5];
    float* out = (float*)d_out;

    const int nsamp  = in_sizes[0] / 8;             // 65536
    const int groups = (nsamp + 1) / 2;             // 2 samples per 16-lane group
    const int total_threads = groups * 16;
    const int blocks = (total_threads + 255) / 256; // 2048

    hipLaunchKernelGGL(qae_fused, dim3(blocks), dim3(256), 0, stream,
                       x, qw, w1, b1, w2, b2, out, nsamp);
}